// Round 9
// baseline (448.719 us; speedup 1.0000x reference)
//
#include <hip/hip_runtime.h>
#include <hip/hip_fp16.h>
#include <stdint.h>

#define NN 100000
#define NE 1250000
#define DD 64
#define NL 4
#define SCAN_B 1024
#define SCAN_NB ((NN + SCAN_B - 1) / SCAN_B)   // 98

#define NPART 8              // XCD partitions
#define PSIZE ((NN + NPART - 1) / NPART)          // 12500 dst nodes / partition
#define TILE4 1024           // int4s per radix tile = 4096 edges
#define NTB ((NE / 4 + TILE4 - 1) / TILE4)        // 306 tiles
#define NSLICE 64            // blocks per partition for hist/fill

#define MB2 64               // nodes per MFMA layer block
#define L2BLOCKS ((NN + MB2 - 1) / MB2)   // 1563
#define APAD 136             // halfs per A/Bt LDS row
#define CPADH 72             // halfs per C row
#define CPADF 68             // floats per C row

typedef _Float16 half8 __attribute__((ext_vector_type(8)));
typedef float floatx4 __attribute__((ext_vector_type(4)));
typedef int intx4 __attribute__((ext_vector_type(4)));

__device__ __forceinline__ float2 h2f2(unsigned u) {
    __half2 h = *reinterpret_cast<__half2*>(&u);
    return __half22float2(h);
}
__device__ __forceinline__ unsigned f2h2(float a, float b) {
    __half2 h = __floats2half2_rn(a, b);
    return *reinterpret_cast<unsigned*>(&h);
}

// ---- x (fp32) -> hh (fp16) ----
__global__ __launch_bounds__(256) void cast_kernel(const float* __restrict__ x,
                                                   __half* __restrict__ hh) {
    int i = blockIdx.x * 256 + threadIdx.x;
    float4 v = ((const float4*)x)[i];
    uint2 u;
    u.x = f2h2(v.x, v.y);
    u.y = f2h2(v.z, v.w);
    ((uint2*)hh)[i] = u;
}

// ---------------- radix bucketing: edges -> 8 dst-partition buckets ----------------
// pass A: per-tile per-bucket counts (bucket-major layout: blockcnt[k*NTB + tile])
__global__ __launch_bounds__(256) void countA_kernel(const int* __restrict__ dst,
                                                     int* __restrict__ blockcnt) {
    __shared__ int cnt[NPART];
    int tid = threadIdx.x;
    if (tid < NPART) cnt[tid] = 0;
    __syncthreads();
    int b = blockIdx.x;
    #pragma unroll
    for (int r = 0; r < 4; ++r) {
        int i4 = b * TILE4 + r * 256 + tid;
        if (i4 < NE / 4) {
            intx4 d = __builtin_nontemporal_load(&((const intx4*)dst)[i4]);
            atomicAdd(&cnt[(unsigned)d.x / PSIZE], 1);
            atomicAdd(&cnt[(unsigned)d.y / PSIZE], 1);
            atomicAdd(&cnt[(unsigned)d.z / PSIZE], 1);
            atomicAdd(&cnt[(unsigned)d.w / PSIZE], 1);
        }
    }
    __syncthreads();
    if (tid < NPART) blockcnt[tid * NTB + b] = cnt[tid];
}

// exclusive scan over the 8*NTB = 2448 counts (bucket-major -> global offsets)
__global__ __launch_bounds__(1024) void scanA_kernel(int* __restrict__ blockcnt) {
    __shared__ int sm[1024];
    const int n = NPART * NTB;          // 2448
    int tid = threadIdx.x;
    int base = tid * 3;
    int e[3];
    int s = 0;
    #pragma unroll
    for (int j = 0; j < 3; ++j) {
        e[j] = (base + j < n) ? blockcnt[base + j] : 0;
        s += e[j];
    }
    sm[tid] = s;
    __syncthreads();
    for (int off = 1; off < 1024; off <<= 1) {
        int v = (tid >= off) ? sm[tid - off] : 0;
        __syncthreads();
        sm[tid] += v;
        __syncthreads();
    }
    int run = sm[tid] - s;              // exclusive base for this thread
    #pragma unroll
    for (int j = 0; j < 3; ++j) {
        if (base + j < n) {
            blockcnt[base + j] = run;
            run += e[j];
        }
    }
}

// pass B: scatter (src,dst) into per-bucket arrays at scanned offsets (no global atomics)
__global__ __launch_bounds__(256) void scatterA_kernel(const int* __restrict__ src,
                                                       const int* __restrict__ dst,
                                                       const int* __restrict__ blockcnt,
                                                       int* __restrict__ ebufS,
                                                       int* __restrict__ ebufD) {
    __shared__ int cur[NPART];
    int tid = threadIdx.x;
    int b = blockIdx.x;
    if (tid < NPART) cur[tid] = blockcnt[tid * NTB + b];
    __syncthreads();
    #pragma unroll
    for (int r = 0; r < 4; ++r) {
        int i4 = b * TILE4 + r * 256 + tid;
        if (i4 < NE / 4) {
            intx4 d = __builtin_nontemporal_load(&((const intx4*)dst)[i4]);
            intx4 s = __builtin_nontemporal_load(&((const intx4*)src)[i4]);
            int p;
            p = atomicAdd(&cur[(unsigned)d.x / PSIZE], 1); ebufS[p] = s.x; ebufD[p] = d.x;
            p = atomicAdd(&cur[(unsigned)d.y / PSIZE], 1); ebufS[p] = s.y; ebufD[p] = d.y;
            p = atomicAdd(&cur[(unsigned)d.z / PSIZE], 1); ebufS[p] = s.z; ebufD[p] = d.z;
            p = atomicAdd(&cur[(unsigned)d.w / PSIZE], 1); ebufS[p] = s.w; ebufD[p] = d.w;
        }
    }
}

// partition-local histogram from bucketed dsts (sequential 1.25MB per XCD)
__global__ __launch_bounds__(256) void histB_kernel(const int* __restrict__ ebufD,
                                                    const int* __restrict__ blockcnt,
                                                    int* __restrict__ deg) {
    int part = blockIdx.x & (NPART - 1);
    int slice = blockIdx.x >> 3;
    int lo = blockcnt[part * NTB];
    int hi = (part < NPART - 1) ? blockcnt[(part + 1) * NTB] : NE;
    int len = hi - lo;
    int per = (len + NSLICE - 1) / NSLICE;
    int s0 = lo + slice * per;
    int s1 = s0 + per; if (s1 > hi) s1 = hi;
    for (int i = s0 + threadIdx.x; i < s1; i += 256)
        atomicAdd(&deg[ebufD[i]], 1);
}

__global__ __launch_bounds__(SCAN_B) void scan1_kernel(const int* __restrict__ deg,
                                                       int* __restrict__ row_start,
                                                       int* __restrict__ blocksums) {
    __shared__ int sm[SCAN_B];
    int tid = threadIdx.x;
    int i = blockIdx.x * SCAN_B + tid;
    int d = (i < NN) ? deg[i] : 0;
    sm[tid] = d;
    __syncthreads();
    for (int off = 1; off < SCAN_B; off <<= 1) {
        int v = (tid >= off) ? sm[tid - off] : 0;
        __syncthreads();
        sm[tid] += v;
        __syncthreads();
    }
    if (i < NN) row_start[i] = sm[tid] - d;
    if (tid == SCAN_B - 1) blocksums[blockIdx.x] = sm[tid];
}

__global__ __launch_bounds__(128) void scan2_kernel(int* __restrict__ blocksums) {
    __shared__ int sm[128];
    int tid = threadIdx.x;
    int v = (tid < SCAN_NB) ? blocksums[tid] : 0;
    sm[tid] = v;
    __syncthreads();
    for (int off = 1; off < 128; off <<= 1) {
        int t = (tid >= off) ? sm[tid - off] : 0;
        __syncthreads();
        sm[tid] += t;
        __syncthreads();
    }
    if (tid < SCAN_NB) blocksums[tid] = sm[tid] - v;   // exclusive
}

__global__ __launch_bounds__(SCAN_B) void scan3_kernel(int* __restrict__ row_start,
                                                       const int* __restrict__ blocksums) {
    int i = blockIdx.x * SCAN_B + threadIdx.x;
    if (i < NN) row_start[i] += blocksums[blockIdx.x];
    if (blockIdx.x == 0 && threadIdx.x == 0) row_start[NN] = NE;
}

// partition-local fill from buckets; csr scatter stays in a ~640KB L2-resident
// window (no cross-stream thrash). Slot via atomicSub countdown on deg.
__global__ __launch_bounds__(256) void fillB_kernel(const int* __restrict__ ebufS,
                                                    const int* __restrict__ ebufD,
                                                    const int* __restrict__ blockcnt,
                                                    const int* __restrict__ row_start,
                                                    int* __restrict__ deg,
                                                    int* __restrict__ csr) {
    int part = blockIdx.x & (NPART - 1);
    int slice = blockIdx.x >> 3;
    int lo = blockcnt[part * NTB];
    int hi = (part < NPART - 1) ? blockcnt[(part + 1) * NTB] : NE;
    int len = hi - lo;
    int per = (len + NSLICE - 1) / NSLICE;
    int s0 = lo + slice * per;
    int s1 = s0 + per; if (s1 > hi) s1 = hi;
    for (int i = s0 + threadIdx.x; i < s1; i += 256) {
        int d = ebufD[i];
        int s = ebufS[i];
        int p = atomicSub(&deg[d], 1) - 1;
        csr[row_start[d] + p] = s;
    }
}

// ---------------- per-layer gather-max (fp16 rows) ----------------
// exec-masked tail (no clamped duplicate loads): loads exactly cnt rows.
__global__ __launch_bounds__(256) void agg_kernel(const __half* __restrict__ hh,
                                                  const int* __restrict__ row_start,
                                                  const int* __restrict__ csr,
                                                  __half* __restrict__ aggh) {
    int tid = threadIdx.x;
    int wv = tid >> 6;
    int lane = tid & 63;
    int g = lane >> 3;              // neighbor sub-slot 0..7
    int c8 = (lane & 7) * 8;        // column base (halfs)
    int n = blockIdx.x * 4 + wv;    // NN = 25000*4 exactly
    int base = row_start[n];
    int cnt = row_start[n + 1] - base;

    if (cnt > 0) {
        const float NI = -__builtin_huge_valf();
        float acc[8];
        #pragma unroll
        for (int i = 0; i < 8; ++i) acc[i] = NI;
        for (int k = 0; k < cnt; k += 16) {
            int k0 = k + g;
            int k1 = k + g + 8;
            if (k0 < cnt) {
                int s0 = __builtin_nontemporal_load(&csr[base + k0]);
                uint4 u0 = *(const uint4*)&hh[(size_t)s0 * DD + c8];
                float2 p;
                p = h2f2(u0.x); acc[0] = fmaxf(acc[0], p.x); acc[1] = fmaxf(acc[1], p.y);
                p = h2f2(u0.y); acc[2] = fmaxf(acc[2], p.x); acc[3] = fmaxf(acc[3], p.y);
                p = h2f2(u0.z); acc[4] = fmaxf(acc[4], p.x); acc[5] = fmaxf(acc[5], p.y);
                p = h2f2(u0.w); acc[6] = fmaxf(acc[6], p.x); acc[7] = fmaxf(acc[7], p.y);
            }
            if (k1 < cnt) {
                int s1 = __builtin_nontemporal_load(&csr[base + k1]);
                uint4 u1 = *(const uint4*)&hh[(size_t)s1 * DD + c8];
                float2 q;
                q = h2f2(u1.x); acc[0] = fmaxf(acc[0], q.x); acc[1] = fmaxf(acc[1], q.y);
                q = h2f2(u1.y); acc[2] = fmaxf(acc[2], q.x); acc[3] = fmaxf(acc[3], q.y);
                q = h2f2(u1.z); acc[4] = fmaxf(acc[4], q.x); acc[5] = fmaxf(acc[5], q.y);
                q = h2f2(u1.w); acc[6] = fmaxf(acc[6], q.x); acc[7] = fmaxf(acc[7], q.y);
            }
        }
        #pragma unroll
        for (int i = 0; i < 8; ++i) {
            acc[i] = fmaxf(acc[i], __shfl_xor(acc[i], 8, 64));
            acc[i] = fmaxf(acc[i], __shfl_xor(acc[i], 16, 64));
            acc[i] = fmaxf(acc[i], __shfl_xor(acc[i], 32, 64));
        }
        if (lane < 8) {
            uint4 u;
            u.x = f2h2(acc[0], acc[1]);
            u.y = f2h2(acc[2], acc[3]);
            u.z = f2h2(acc[4], acc[5]);
            u.w = f2h2(acc[6], acc[7]);
            *(uint4*)&aggh[(size_t)n * DD + lane * 8] = u;
        }
    } else {
        if (lane < 8) {
            uint4 z = make_uint4(0, 0, 0, 0);   // PyG empty-segment -> 0
            *(uint4*)&aggh[(size_t)n * DD + lane * 8] = z;
        }
    }
}

// ---------------- dense update via MFMA ----------------
__global__ __launch_bounds__(256, 4) void layer_mfma_kernel(
        const __half* __restrict__ aggh,
        __half* __restrict__ hh,
        float* __restrict__ hout,
        const float* __restrict__ Wl,
        const float* __restrict__ bl,
        const float* __restrict__ Wr,
        int last) {
    __shared__ char smem[2 * MB2 * APAD * 2];   // 34816 B, reused by epilogue
    _Float16* a_s  = (_Float16*)smem;                          // [64][APAD]
    _Float16* bt_s = (_Float16*)(smem + MB2 * APAD * 2);       // [64][APAD], n-major

    int tid = threadIdx.x;
    int lane = tid & 63;
    int w = tid >> 6;
    int node0 = blockIdx.x * MB2;

    #pragma unroll
    for (int i = 0; i < 4; ++i) {
        int idx = i * 256 + tid;          // uint4 id, 1024 total
        int r = idx >> 4;
        int c4 = idx & 15;
        int node = node0 + r; if (node > NN - 1) node = NN - 1;
        const __half* srcp = (c4 < 8) ? (aggh + (size_t)node * DD + c4 * 8)
                                      : (hh + (size_t)node * DD + (c4 - 8) * 8);
        uint4 v = *(const uint4*)srcp;
        *(uint4*)&a_s[r * APAD + c4 * 8] = v;
    }
    {
        int n = tid & 63;
        int kb = tid >> 6;
        #pragma unroll
        for (int kk = 0; kk < 32; ++kk) {
            int k = kb * 32 + kk;
            float wv = (k < 64) ? Wl[k * DD + n] : Wr[(k - 64) * DD + n];
            bt_s[n * APAD + k] = (_Float16)wv;
        }
    }
    __syncthreads();

    floatx4 acc[4];
    #pragma unroll
    for (int nt = 0; nt < 4; ++nt) acc[nt] = (floatx4){0.f, 0.f, 0.f, 0.f};
    int m = lane & 15;
    int q = lane >> 4;

    #pragma unroll
    for (int ks = 0; ks < 4; ++ks) {
        half8 af = *(half8*)&a_s[(w * 16 + m) * APAD + q * 8 + ks * 32];
        #pragma unroll
        for (int nt = 0; nt < 4; ++nt) {
            half8 bf = *(half8*)&bt_s[(nt * 16 + m) * APAD + q * 8 + ks * 32];
            acc[nt] = __builtin_amdgcn_mfma_f32_16x16x32_f16(af, bf, acc[nt], 0, 0, 0);
        }
    }
    __syncthreads();

    _Float16* ch = (_Float16*)smem;                      // [64][CPADH]
    float*    cf = (float*)(smem + MB2 * CPADH * 2);     // [64][CPADF]

    #pragma unroll
    for (int nt = 0; nt < 4; ++nt) {
        int col = nt * 16 + m;
        float b = bl[col];
        #pragma unroll
        for (int r = 0; r < 4; ++r) {
            int rowl = w * 16 + q * 4 + r;
            float o = fmaxf(acc[nt][r] + b, 0.0f);
            ch[rowl * CPADH + col] = (_Float16)o;
            if (last) cf[rowl * CPADF + col] = o;
        }
    }
    __syncthreads();

    #pragma unroll
    for (int i = 0; i < 2; ++i) {
        int idx = i * 256 + tid;          // 512 uint4s
        int r = idx >> 3;
        int c4 = idx & 7;
        int node = node0 + r;
        if (node < NN) {
            uint4 v = *(uint4*)&ch[r * CPADH + c4 * 8];
            *(uint4*)&hh[(size_t)node * DD + c4 * 8] = v;
        }
    }
    if (last) {
        #pragma unroll
        for (int i = 0; i < 4; ++i) {
            int idx = i * 256 + tid;      // 1024 float4s
            int r = idx >> 4;
            int c4 = idx & 15;
            int node = node0 + r;
            if (node < NN) {
                float4 v = *(float4*)&cf[r * CPADF + c4 * 4];
                *(float4*)&hout[(size_t)node * DD + c4 * 4] = v;
            }
        }
    }
}

extern "C" void kernel_launch(void* const* d_in, const int* in_sizes, int n_in,
                              void* d_out, int out_size, void* d_ws, size_t ws_size,
                              hipStream_t stream) {
    const float* x  = (const float*)d_in[0];
    const int*   ei = (const int*)d_in[1];
    const float* Wl = (const float*)d_in[2];
    const float* bl = (const float*)d_in[3];
    const float* Wr = (const float*)d_in[4];
    float* h = (float*)d_out;

    const int* src = ei;
    const int* dst = ei + NE;

    char* ws = (char*)d_ws;
    __half* aggh     = (__half*)ws;  ws += (size_t)NN * DD * sizeof(__half);  // 12.8 MB
    __half* hh       = (__half*)ws;  ws += (size_t)NN * DD * sizeof(__half);  // 12.8 MB
    int* row_start   = (int*)ws;     ws += (size_t)(NN + 16) * sizeof(int);
    int* deg         = (int*)ws;     ws += (size_t)NN * sizeof(int);
    int* blocksums   = (int*)ws;     ws += 128 * sizeof(int);
    int* blockcnt    = (int*)ws;     ws += (size_t)(NPART * NTB + 16) * sizeof(int);
    int* csr         = (int*)ws;                                              // 5 MB

    // edge buckets reuse the aggh region (dead until first agg_kernel)
    int* ebufS = (int*)aggh;
    int* ebufD = ebufS + NE;                     // 2*NE ints = 10 MB <= 12.8 MB

    cast_kernel<<<(NN * DD / 4) / 256, 256, 0, stream>>>(x, hh);
    hipMemsetAsync(deg, 0, (size_t)NN * sizeof(int), stream);

    countA_kernel<<<NTB, 256, 0, stream>>>(dst, blockcnt);
    scanA_kernel<<<1, 1024, 0, stream>>>(blockcnt);
    scatterA_kernel<<<NTB, 256, 0, stream>>>(src, dst, blockcnt, ebufS, ebufD);
    histB_kernel<<<NPART * NSLICE, 256, 0, stream>>>(ebufD, blockcnt, deg);
    scan1_kernel<<<SCAN_NB, SCAN_B, 0, stream>>>(deg, row_start, blocksums);
    scan2_kernel<<<1, 128, 0, stream>>>(blocksums);
    scan3_kernel<<<SCAN_NB, SCAN_B, 0, stream>>>(row_start, blocksums);
    fillB_kernel<<<NPART * NSLICE, 256, 0, stream>>>(ebufS, ebufD, blockcnt, row_start, deg, csr);

    for (int l = 0; l < NL; ++l) {
        agg_kernel<<<NN / 4, 256, 0, stream>>>(hh, row_start, csr, aggh);
        layer_mfma_kernel<<<L2BLOCKS, 256, 0, stream>>>(
            aggh, hh, h, Wl + (size_t)l * DD * DD, bl + (size_t)l * DD, Wr + (size_t)l * DD * DD,
            (l == NL - 1) ? 1 : 0);
    }
}

// Round 11
// 355.036 us; speedup vs baseline: 1.2639x; 1.2639x over previous
//
#include <hip/hip_runtime.h>
#include <hip/hip_fp16.h>
#include <stdint.h>

#define NN 100000
#define NE 1250000
#define DD 64
#define NL 4
#define SCAN_B 1024
#define SCAN_NB ((NN + SCAN_B - 1) / SCAN_B)   // 98

#define NPART 8              // XCD partitions
#define PSIZE ((NN + NPART - 1) / NPART)          // 12500 dst nodes / partition
#define TILE4 1024           // int4s per radix tile = 4096 edges
#define NTB ((NE / 4 + TILE4 - 1) / TILE4)        // 306 tiles
#define NSLICE 64            // blocks per partition for histBR/fillBF

#define MB2 64               // nodes per MFMA layer block
#define L2BLOCKS ((NN + MB2 - 1) / MB2)   // 1563
#define APAD 136             // halfs per A/Bt LDS row
#define CPADH 72             // halfs per C row
#define CPADF 68             // floats per C row

typedef _Float16 half8 __attribute__((ext_vector_type(8)));
typedef _Float16 half2v __attribute__((ext_vector_type(2)));
typedef float floatx4 __attribute__((ext_vector_type(4)));
typedef int intx4 __attribute__((ext_vector_type(4)));

__device__ __forceinline__ float2 h2f2(unsigned u) {
    __half2 h = *reinterpret_cast<__half2*>(&u);
    return __half22float2(h);
}
__device__ __forceinline__ unsigned f2h2(float a, float b) {
    __half2 h = __floats2half2_rn(a, b);
    return *reinterpret_cast<unsigned*>(&h);
}
// packed fp16 max on raw bits (maps to v_pk_max_f16)
__device__ __forceinline__ unsigned umax2(unsigned a, unsigned b) {
    half2v x = *reinterpret_cast<half2v*>(&a);
    half2v y = *reinterpret_cast<half2v*>(&b);
    half2v r = __builtin_elementwise_max(x, y);
    return *reinterpret_cast<unsigned*>(&r);
}

// ---- x (fp32) -> hh (fp16) ----
__global__ __launch_bounds__(256) void cast_kernel(const float* __restrict__ x,
                                                   __half* __restrict__ hh) {
    int i = blockIdx.x * 256 + threadIdx.x;
    float4 v = ((const float4*)x)[i];
    uint2 u;
    u.x = f2h2(v.x, v.y);
    u.y = f2h2(v.z, v.w);
    ((uint2*)hh)[i] = u;
}

// ---------------- radix bucketing: edges -> 8 dst-partition buckets ----------------
__global__ __launch_bounds__(256) void countA_kernel(const int* __restrict__ dst,
                                                     int* __restrict__ blockcnt) {
    __shared__ int cnt[NPART];
    int tid = threadIdx.x;
    if (tid < NPART) cnt[tid] = 0;
    __syncthreads();
    int b = blockIdx.x;
    #pragma unroll
    for (int r = 0; r < 4; ++r) {
        int i4 = b * TILE4 + r * 256 + tid;
        if (i4 < NE / 4) {
            intx4 d = __builtin_nontemporal_load(&((const intx4*)dst)[i4]);
            atomicAdd(&cnt[(unsigned)d.x / PSIZE], 1);
            atomicAdd(&cnt[(unsigned)d.y / PSIZE], 1);
            atomicAdd(&cnt[(unsigned)d.z / PSIZE], 1);
            atomicAdd(&cnt[(unsigned)d.w / PSIZE], 1);
        }
    }
    __syncthreads();
    if (tid < NPART) blockcnt[tid * NTB + b] = cnt[tid];
}

__global__ __launch_bounds__(1024) void scanA_kernel(int* __restrict__ blockcnt) {
    __shared__ int sm[1024];
    const int n = NPART * NTB;          // 2448
    int tid = threadIdx.x;
    int base = tid * 3;
    int e[3];
    int s = 0;
    #pragma unroll
    for (int j = 0; j < 3; ++j) {
        e[j] = (base + j < n) ? blockcnt[base + j] : 0;
        s += e[j];
    }
    sm[tid] = s;
    __syncthreads();
    for (int off = 1; off < 1024; off <<= 1) {
        int v = (tid >= off) ? sm[tid - off] : 0;
        __syncthreads();
        sm[tid] += v;
        __syncthreads();
    }
    int run = sm[tid] - s;
    #pragma unroll
    for (int j = 0; j < 3; ++j) {
        if (base + j < n) {
            blockcnt[base + j] = run;
            run += e[j];
        }
    }
}

__global__ __launch_bounds__(256) void scatterA_kernel(const int* __restrict__ src,
                                                       const int* __restrict__ dst,
                                                       const int* __restrict__ blockcnt,
                                                       int* __restrict__ ebufS,
                                                       int* __restrict__ ebufD) {
    __shared__ int cur[NPART];
    int tid = threadIdx.x;
    int b = blockIdx.x;
    if (tid < NPART) cur[tid] = blockcnt[tid * NTB + b];
    __syncthreads();
    #pragma unroll
    for (int r = 0; r < 4; ++r) {
        int i4 = b * TILE4 + r * 256 + tid;
        if (i4 < NE / 4) {
            intx4 d = __builtin_nontemporal_load(&((const intx4*)dst)[i4]);
            intx4 s = __builtin_nontemporal_load(&((const intx4*)src)[i4]);
            int p;
            p = atomicAdd(&cur[(unsigned)d.x / PSIZE], 1); ebufS[p] = s.x; ebufD[p] = d.x;
            p = atomicAdd(&cur[(unsigned)d.y / PSIZE], 1); ebufS[p] = s.y; ebufD[p] = d.y;
            p = atomicAdd(&cur[(unsigned)d.z / PSIZE], 1); ebufS[p] = s.z; ebufD[p] = d.z;
            p = atomicAdd(&cur[(unsigned)d.w / PSIZE], 1); ebufS[p] = s.w; ebufD[p] = d.w;
        }
    }
}

// ---- ONE atomic pass: partition-local hist; atomicAdd return = edge rank,
// stored COALESCED in bucket order (sequential i). ----
__global__ __launch_bounds__(256) void histBR_kernel(const int* __restrict__ ebufD,
                                                     const int* __restrict__ blockcnt,
                                                     int* __restrict__ deg,
                                                     int* __restrict__ ebufR) {
    int part = blockIdx.x & (NPART - 1);
    int slice = blockIdx.x >> 3;
    int lo = blockcnt[part * NTB];
    int hi = (part < NPART - 1) ? blockcnt[(part + 1) * NTB] : NE;
    int len = hi - lo;
    int per = (len + NSLICE - 1) / NSLICE;
    int s0 = lo + slice * per;
    int s1 = s0 + per; if (s1 > hi) s1 = hi;
    for (int i = s0 + threadIdx.x; i < s1; i += 256) {
        int d = ebufD[i];
        ebufR[i] = atomicAdd(&deg[d], 1);
    }
}

__global__ __launch_bounds__(SCAN_B) void scan1_kernel(const int* __restrict__ deg,
                                                       int* __restrict__ row_start,
                                                       int* __restrict__ blocksums) {
    __shared__ int sm[SCAN_B];
    int tid = threadIdx.x;
    int i = blockIdx.x * SCAN_B + tid;
    int d = (i < NN) ? deg[i] : 0;
    sm[tid] = d;
    __syncthreads();
    for (int off = 1; off < SCAN_B; off <<= 1) {
        int v = (tid >= off) ? sm[tid - off] : 0;
        __syncthreads();
        sm[tid] += v;
        __syncthreads();
    }
    if (i < NN) row_start[i] = sm[tid] - d;
    if (tid == SCAN_B - 1) blocksums[blockIdx.x] = sm[tid];
}

__global__ __launch_bounds__(128) void scan2_kernel(int* __restrict__ blocksums) {
    __shared__ int sm[128];
    int tid = threadIdx.x;
    int v = (tid < SCAN_NB) ? blocksums[tid] : 0;
    sm[tid] = v;
    __syncthreads();
    for (int off = 1; off < 128; off <<= 1) {
        int t = (tid >= off) ? sm[tid - off] : 0;
        __syncthreads();
        sm[tid] += t;
        __syncthreads();
    }
    if (tid < SCAN_NB) blocksums[tid] = sm[tid] - v;   // exclusive
}

__global__ __launch_bounds__(SCAN_B) void scan3_kernel(int* __restrict__ row_start,
                                                       const int* __restrict__ blocksums) {
    int i = blockIdx.x * SCAN_B + threadIdx.x;
    if (i < NN) row_start[i] += blocksums[blockIdx.x];
    if (blockIdx.x == 0 && threadIdx.x == 0) row_start[NN] = NE;
}

// ---- atomic-FREE fill: sequential bucket reads, csr scatter stays in the
// partition's ~640KB window on (heuristically) one XCD. ----
__global__ __launch_bounds__(256) void fillBF_kernel(const int* __restrict__ ebufS,
                                                     const int* __restrict__ ebufD,
                                                     const int* __restrict__ ebufR,
                                                     const int* __restrict__ blockcnt,
                                                     const int* __restrict__ row_start,
                                                     int* __restrict__ csr) {
    int part = blockIdx.x & (NPART - 1);
    int slice = blockIdx.x >> 3;
    int lo = blockcnt[part * NTB];
    int hi = (part < NPART - 1) ? blockcnt[(part + 1) * NTB] : NE;
    int len = hi - lo;
    int per = (len + NSLICE - 1) / NSLICE;
    int s0 = lo + slice * per;
    int s1 = s0 + per; if (s1 > hi) s1 = hi;
    for (int i = s0 + threadIdx.x; i < s1; i += 256) {
        int d = ebufD[i];
        csr[row_start[d] + ebufR[i]] = ebufS[i];
    }
}

// ---------------- per-layer gather-max (fp16 rows, packed half2 max) ----------------
// one wave per node; 8-lane groups x 16B = one 128B row, 16 neighbors/iter.
// csr indices preloaded once (coalesced, one per lane) + shfl broadcast: breaks
// the csr->row serial latency chain. Max in packed half2 (bit-exact, 4 VALU
// ops/row). cnt>64 tail falls back to direct csr loads (P ~ 0 for this graph).
__global__ __launch_bounds__(256) void agg_kernel(const __half* __restrict__ hh,
                                                  const int* __restrict__ row_start,
                                                  const int* __restrict__ csr,
                                                  __half* __restrict__ aggh) {
    int tid = threadIdx.x;
    int wv = tid >> 6;
    int lane = tid & 63;
    int g = lane >> 3;              // neighbor sub-slot 0..7
    int c8 = (lane & 7) * 8;        // column base (halfs)
    int n = blockIdx.x * 4 + wv;    // NN = 25000*4 exactly
    int base = row_start[n];
    int cnt = row_start[n + 1] - base;

    if (cnt > 0) {
        int clampi = cnt - 1;
        int pre = (lane <= clampi) ? lane : clampi;
        int idx = csr[base + pre];              // coalesced 256B index preload

        uint4 acc = make_uint4(0xFC00FC00u, 0xFC00FC00u, 0xFC00FC00u, 0xFC00FC00u);
        int kmax = (cnt < 64) ? cnt : 64;
        for (int k = 0; k < kmax; k += 16) {
            int k0 = k + g;
            int k1 = k + g + 8;
            int s0 = __shfl(idx, (k0 <= clampi) ? k0 : clampi, 64);
            int s1 = __shfl(idx, (k1 <= clampi) ? k1 : clampi, 64);
            if (k0 < cnt) {
                uint4 u0 = *(const uint4*)&hh[(size_t)s0 * DD + c8];
                acc.x = umax2(acc.x, u0.x);
                acc.y = umax2(acc.y, u0.y);
                acc.z = umax2(acc.z, u0.z);
                acc.w = umax2(acc.w, u0.w);
            }
            if (k1 < cnt) {
                uint4 u1 = *(const uint4*)&hh[(size_t)s1 * DD + c8];
                acc.x = umax2(acc.x, u1.x);
                acc.y = umax2(acc.y, u1.y);
                acc.z = umax2(acc.z, u1.z);
                acc.w = umax2(acc.w, u1.w);
            }
        }
        for (int k = 64 + g; k < cnt; k += 8) {   // ultra-rare tail
            int s = csr[base + k];
            uint4 u = *(const uint4*)&hh[(size_t)s * DD + c8];
            acc.x = umax2(acc.x, u.x);
            acc.y = umax2(acc.y, u.y);
            acc.z = umax2(acc.z, u.z);
            acc.w = umax2(acc.w, u.w);
        }
        // cross-group reduce (xor 8/16/32) in packed half2
        #pragma unroll
        for (int off = 8; off <= 32; off <<= 1) {
            acc.x = umax2(acc.x, (unsigned)__shfl_xor((int)acc.x, off, 64));
            acc.y = umax2(acc.y, (unsigned)__shfl_xor((int)acc.y, off, 64));
            acc.z = umax2(acc.z, (unsigned)__shfl_xor((int)acc.z, off, 64));
            acc.w = umax2(acc.w, (unsigned)__shfl_xor((int)acc.w, off, 64));
        }
        if (lane < 8) *(uint4*)&aggh[(size_t)n * DD + c8] = acc;
    } else {
        if (lane < 8) {
            uint4 z = make_uint4(0, 0, 0, 0);   // PyG empty-segment -> 0
            *(uint4*)&aggh[(size_t)n * DD + c8] = z;
        }
    }
}

// ---------------- dense update via MFMA ----------------
__global__ __launch_bounds__(256, 4) void layer_mfma_kernel(
        const __half* __restrict__ aggh,
        __half* __restrict__ hh,
        float* __restrict__ hout,
        const float* __restrict__ Wl,
        const float* __restrict__ bl,
        const float* __restrict__ Wr,
        int last) {
    __shared__ char smem[2 * MB2 * APAD * 2];   // 34816 B, reused by epilogue
    _Float16* a_s  = (_Float16*)smem;                          // [64][APAD]
    _Float16* bt_s = (_Float16*)(smem + MB2 * APAD * 2);       // [64][APAD], n-major

    int tid = threadIdx.x;
    int lane = tid & 63;
    int w = tid >> 6;
    int node0 = blockIdx.x * MB2;

    #pragma unroll
    for (int i = 0; i < 4; ++i) {
        int idx = i * 256 + tid;          // uint4 id, 1024 total
        int r = idx >> 4;
        int c4 = idx & 15;
        int node = node0 + r; if (node > NN - 1) node = NN - 1;
        const __half* srcp = (c4 < 8) ? (aggh + (size_t)node * DD + c4 * 8)
                                      : (hh + (size_t)node * DD + (c4 - 8) * 8);
        uint4 v = *(const uint4*)srcp;
        *(uint4*)&a_s[r * APAD + c4 * 8] = v;
    }
    {
        int n = tid & 63;
        int kb = tid >> 6;
        #pragma unroll
        for (int kk = 0; kk < 32; ++kk) {
            int k = kb * 32 + kk;
            float wv = (k < 64) ? Wl[k * DD + n] : Wr[(k - 64) * DD + n];
            bt_s[n * APAD + k] = (_Float16)wv;
        }
    }
    __syncthreads();

    floatx4 acc[4];
    #pragma unroll
    for (int nt = 0; nt < 4; ++nt) acc[nt] = (floatx4){0.f, 0.f, 0.f, 0.f};
    int m = lane & 15;
    int q = lane >> 4;

    #pragma unroll
    for (int ks = 0; ks < 4; ++ks) {
        half8 af = *(half8*)&a_s[(w * 16 + m) * APAD + q * 8 + ks * 32];
        #pragma unroll
        for (int nt = 0; nt < 4; ++nt) {
            half8 bf = *(half8*)&bt_s[(nt * 16 + m) * APAD + q * 8 + ks * 32];
            acc[nt] = __builtin_amdgcn_mfma_f32_16x16x32_f16(af, bf, acc[nt], 0, 0, 0);
        }
    }
    __syncthreads();

    _Float16* ch = (_Float16*)smem;                      // [64][CPADH]
    float*    cf = (float*)(smem + MB2 * CPADH * 2);     // [64][CPADF]

    #pragma unroll
    for (int nt = 0; nt < 4; ++nt) {
        int col = nt * 16 + m;
        float b = bl[col];
        #pragma unroll
        for (int r = 0; r < 4; ++r) {
            int rowl = w * 16 + q * 4 + r;
            float o = fmaxf(acc[nt][r] + b, 0.0f);
            ch[rowl * CPADH + col] = (_Float16)o;
            if (last) cf[rowl * CPADF + col] = o;
        }
    }
    __syncthreads();

    #pragma unroll
    for (int i = 0; i < 2; ++i) {
        int idx = i * 256 + tid;          // 512 uint4s
        int r = idx >> 3;
        int c4 = idx & 7;
        int node = node0 + r;
        if (node < NN) {
            uint4 v = *(uint4*)&ch[r * CPADH + c4 * 8];
            *(uint4*)&hh[(size_t)node * DD + c4 * 8] = v;
        }
    }
    if (last) {
        #pragma unroll
        for (int i = 0; i < 4; ++i) {
            int idx = i * 256 + tid;      // 1024 float4s
            int r = idx >> 4;
            int c4 = idx & 15;
            int node = node0 + r;
            if (node < NN) {
                float4 v = *(float4*)&cf[r * CPADF + c4 * 4];
                *(float4*)&hout[(size_t)node * DD + c4 * 4] = v;
            }
        }
    }
}

extern "C" void kernel_launch(void* const* d_in, const int* in_sizes, int n_in,
                              void* d_out, int out_size, void* d_ws, size_t ws_size,
                              hipStream_t stream) {
    const float* x  = (const float*)d_in[0];
    const int*   ei = (const int*)d_in[1];
    const float* Wl = (const float*)d_in[2];
    const float* bl = (const float*)d_in[3];
    const float* Wr = (const float*)d_in[4];
    float* h = (float*)d_out;

    const int* src = ei;
    const int* dst = ei + NE;

    char* ws = (char*)d_ws;
    __half* aggh     = (__half*)ws;  ws += (size_t)NN * DD * sizeof(__half);  // 12.8 MB
    __half* hh       = (__half*)ws;  ws += (size_t)NN * DD * sizeof(__half);  // 12.8 MB
    int* row_start   = (int*)ws;     ws += (size_t)(NN + 16) * sizeof(int);
    int* deg         = (int*)ws;     ws += (size_t)NN * sizeof(int);
    int* blocksums   = (int*)ws;     ws += 128 * sizeof(int);
    int* blockcnt    = (int*)ws;     ws += (size_t)(NPART * NTB + 16) * sizeof(int);
    int* ebufR       = (int*)ws;     ws += (size_t)NE * sizeof(int);          // 5 MB
    int* csr         = (int*)ws;                                              // 5 MB

    // edge buckets reuse the aggh region (dead until first agg_kernel)
    int* ebufS = (int*)aggh;
    int* ebufD = ebufS + NE;                     // 2*NE ints = 10 MB <= 12.8 MB

    cast_kernel<<<(NN * DD / 4) / 256, 256, 0, stream>>>(x, hh);
    hipMemsetAsync(deg, 0, (size_t)NN * sizeof(int), stream);

    countA_kernel<<<NTB, 256, 0, stream>>>(dst, blockcnt);
    scanA_kernel<<<1, 1024, 0, stream>>>(blockcnt);
    scatterA_kernel<<<NTB, 256, 0, stream>>>(src, dst, blockcnt, ebufS, ebufD);
    histBR_kernel<<<NPART * NSLICE, 256, 0, stream>>>(ebufD, blockcnt, deg, ebufR);
    scan1_kernel<<<SCAN_NB, SCAN_B, 0, stream>>>(deg, row_start, blocksums);
    scan2_kernel<<<1, 128, 0, stream>>>(blocksums);
    scan3_kernel<<<SCAN_NB, SCAN_B, 0, stream>>>(row_start, blocksums);
    fillBF_kernel<<<NPART * NSLICE, 256, 0, stream>>>(ebufS, ebufD, ebufR, blockcnt, row_start, csr);

    for (int l = 0; l < NL; ++l) {
        agg_kernel<<<NN / 4, 256, 0, stream>>>(hh, row_start, csr, aggh);
        layer_mfma_kernel<<<L2BLOCKS, 256, 0, stream>>>(
            aggh, hh, h, Wl + (size_t)l * DD * DD, bl + (size_t)l * DD, Wr + (size_t)l * DD * DD,
            (l == NL - 1) ? 1 : 0);
    }
}

// Round 12
// 324.671 us; speedup vs baseline: 1.3821x; 1.0935x over previous
//
#include <hip/hip_runtime.h>
#include <hip/hip_fp16.h>
#include <stdint.h>

#define NN 100000
#define NE 1250000
#define DD 64
#define NL 4
#define SCAN_B 1024
#define SCAN_NB ((NN + SCAN_B - 1) / SCAN_B)   // 98

#define NPART2 32            // sub-partitions (LDS-countable)
#define PSIZE2 3125          // nodes per sub-partition
#define WSUB 8               // workgroups per sub-partition for count/fill
#define TILE4 1024           // int4s per radix tile = 4096 edges
#define NTB ((NE / 4 + TILE4 - 1) / TILE4)        // 306 tiles
#define SCANA_N (NPART2 * NTB)                    // 9792

#define MB2 64               // nodes per MFMA layer block
#define L2BLOCKS ((NN + MB2 - 1) / MB2)   // 1563
#define APAD 136             // halfs per A/Bt LDS row
#define CPADH 72             // halfs per C row
#define CPADF 68             // floats per C row

typedef _Float16 half8 __attribute__((ext_vector_type(8)));
typedef _Float16 half2v __attribute__((ext_vector_type(2)));
typedef float floatx4 __attribute__((ext_vector_type(4)));
typedef int intx4 __attribute__((ext_vector_type(4)));

__device__ __forceinline__ float2 h2f2(unsigned u) {
    __half2 h = *reinterpret_cast<__half2*>(&u);
    return __half22float2(h);
}
__device__ __forceinline__ unsigned f2h2(float a, float b) {
    __half2 h = __floats2half2_rn(a, b);
    return *reinterpret_cast<unsigned*>(&h);
}
// packed fp16 max on raw bits (maps to v_pk_max_f16)
__device__ __forceinline__ unsigned umax2(unsigned a, unsigned b) {
    half2v x = *reinterpret_cast<half2v*>(&a);
    half2v y = *reinterpret_cast<half2v*>(&b);
    half2v r = __builtin_elementwise_max(x, y);
    return *reinterpret_cast<unsigned*>(&r);
}

// ---- x (fp32) -> hh (fp16) ----
__global__ __launch_bounds__(256) void cast_kernel(const float* __restrict__ x,
                                                   __half* __restrict__ hh) {
    int i = blockIdx.x * 256 + threadIdx.x;
    float4 v = ((const float4*)x)[i];
    uint2 u;
    u.x = f2h2(v.x, v.y);
    u.y = f2h2(v.z, v.w);
    ((uint2*)hh)[i] = u;
}

// ---------------- radix bucketing: edges -> 32 dst-partition buckets ----------------
__global__ __launch_bounds__(256) void countA_kernel(const int* __restrict__ dst,
                                                     int* __restrict__ blockcnt) {
    __shared__ int cnt[NPART2];
    int tid = threadIdx.x;
    if (tid < NPART2) cnt[tid] = 0;
    __syncthreads();
    int b = blockIdx.x;
    #pragma unroll
    for (int r = 0; r < 4; ++r) {
        int i4 = b * TILE4 + r * 256 + tid;
        if (i4 < NE / 4) {
            intx4 d = __builtin_nontemporal_load(&((const intx4*)dst)[i4]);
            atomicAdd(&cnt[(unsigned)d.x / PSIZE2], 1);
            atomicAdd(&cnt[(unsigned)d.y / PSIZE2], 1);
            atomicAdd(&cnt[(unsigned)d.z / PSIZE2], 1);
            atomicAdd(&cnt[(unsigned)d.w / PSIZE2], 1);
        }
    }
    __syncthreads();
    if (tid < NPART2) blockcnt[tid * NTB + b] = cnt[tid];
}

// exclusive scan over NPART2*NTB = 9792 counts (bucket-major -> global offsets)
__global__ __launch_bounds__(1024) void scanA_kernel(int* __restrict__ blockcnt) {
    __shared__ int sm[1024];
    int tid = threadIdx.x;
    int base = tid * 10;
    int e[10];
    int s = 0;
    #pragma unroll
    for (int j = 0; j < 10; ++j) {
        e[j] = (base + j < SCANA_N) ? blockcnt[base + j] : 0;
        s += e[j];
    }
    sm[tid] = s;
    __syncthreads();
    for (int off = 1; off < 1024; off <<= 1) {
        int v = (tid >= off) ? sm[tid - off] : 0;
        __syncthreads();
        sm[tid] += v;
        __syncthreads();
    }
    int run = sm[tid] - s;
    #pragma unroll
    for (int j = 0; j < 10; ++j) {
        if (base + j < SCANA_N) {
            blockcnt[base + j] = run;
            run += e[j];
        }
    }
}

__global__ __launch_bounds__(256) void scatterA_kernel(const int* __restrict__ src,
                                                       const int* __restrict__ dst,
                                                       const int* __restrict__ blockcnt,
                                                       int* __restrict__ ebufS,
                                                       int* __restrict__ ebufD) {
    __shared__ int cur[NPART2];
    int tid = threadIdx.x;
    int b = blockIdx.x;
    if (tid < NPART2) cur[tid] = blockcnt[tid * NTB + b];
    __syncthreads();
    #pragma unroll
    for (int r = 0; r < 4; ++r) {
        int i4 = b * TILE4 + r * 256 + tid;
        if (i4 < NE / 4) {
            intx4 d = __builtin_nontemporal_load(&((const intx4*)dst)[i4]);
            intx4 s = __builtin_nontemporal_load(&((const intx4*)src)[i4]);
            int p;
            p = atomicAdd(&cur[(unsigned)d.x / PSIZE2], 1); ebufS[p] = s.x; ebufD[p] = d.x;
            p = atomicAdd(&cur[(unsigned)d.y / PSIZE2], 1); ebufS[p] = s.y; ebufD[p] = d.y;
            p = atomicAdd(&cur[(unsigned)d.z / PSIZE2], 1); ebufS[p] = s.z; ebufD[p] = d.z;
            p = atomicAdd(&cur[(unsigned)d.w / PSIZE2], 1); ebufS[p] = s.w; ebufD[p] = d.w;
        }
    }
}

// ---- pass 1 of LDS counting sort: per-WG-slice histogram in LDS (no global atomics) ----
__global__ __launch_bounds__(256) void countC_kernel(const int* __restrict__ ebufD,
                                                     const int* __restrict__ blockcnt,
                                                     int* __restrict__ wgHist) {
    __shared__ int cnt[PSIZE2];
    int part = blockIdx.x & (NPART2 - 1);
    int w = blockIdx.x >> 5;
    int tid = threadIdx.x;
    for (int j = tid; j < PSIZE2; j += 256) cnt[j] = 0;
    __syncthreads();
    int nbase = part * PSIZE2;
    int lo = blockcnt[part * NTB];
    int hi = (part < NPART2 - 1) ? blockcnt[(part + 1) * NTB] : NE;
    int len = hi - lo;
    int per = (len + WSUB - 1) / WSUB;
    int s0 = lo + w * per;
    int s1 = s0 + per; if (s1 > hi) s1 = hi;
    for (int i = s0 + tid; i < s1; i += 256)
        atomicAdd(&cnt[ebufD[i] - nbase], 1);
    __syncthreads();
    int* out = wgHist + (size_t)(part * WSUB + w) * PSIZE2;
    for (int j = tid; j < PSIZE2; j += 256) out[j] = cnt[j];
}

// ---- pass 2: per-node sum + exclusive prefix over the WSUB histograms ----
__global__ __launch_bounds__(256) void sumC_kernel(int* __restrict__ wgHist,
                                                   int* __restrict__ deg) {
    int i = blockIdx.x * 256 + threadIdx.x;
    if (i < NN) {
        int part = (unsigned)i / PSIZE2;
        int j = i - part * PSIZE2;
        int run = 0;
        #pragma unroll
        for (int w = 0; w < WSUB; ++w) {
            size_t idx = (size_t)(part * WSUB + w) * PSIZE2 + j;
            int v = wgHist[idx];
            wgHist[idx] = run;        // becomes per-WG exclusive base
            run += v;
        }
        deg[i] = run;
    }
}

__global__ __launch_bounds__(SCAN_B) void scan1_kernel(const int* __restrict__ deg,
                                                       int* __restrict__ row_start,
                                                       int* __restrict__ blocksums) {
    __shared__ int sm[SCAN_B];
    int tid = threadIdx.x;
    int i = blockIdx.x * SCAN_B + tid;
    int d = (i < NN) ? deg[i] : 0;
    sm[tid] = d;
    __syncthreads();
    for (int off = 1; off < SCAN_B; off <<= 1) {
        int v = (tid >= off) ? sm[tid - off] : 0;
        __syncthreads();
        sm[tid] += v;
        __syncthreads();
    }
    if (i < NN) row_start[i] = sm[tid] - d;
    if (tid == SCAN_B - 1) blocksums[blockIdx.x] = sm[tid];
}

__global__ __launch_bounds__(128) void scan2_kernel(int* __restrict__ blocksums) {
    __shared__ int sm[128];
    int tid = threadIdx.x;
    int v = (tid < SCAN_NB) ? blocksums[tid] : 0;
    sm[tid] = v;
    __syncthreads();
    for (int off = 1; off < 128; off <<= 1) {
        int t = (tid >= off) ? sm[tid - off] : 0;
        __syncthreads();
        sm[tid] += t;
        __syncthreads();
    }
    if (tid < SCAN_NB) blocksums[tid] = sm[tid] - v;   // exclusive
}

__global__ __launch_bounds__(SCAN_B) void scan3_kernel(int* __restrict__ row_start,
                                                       const int* __restrict__ blocksums) {
    int i = blockIdx.x * SCAN_B + threadIdx.x;
    if (i < NN) row_start[i] += blocksums[blockIdx.x];
    if (blockIdx.x == 0 && threadIdx.x == 0) row_start[NN] = NE;
}

// ---- pass 3: fill csr; rank = LDS wgBase + LDS cnt++ (LDS atomics only).
// row_start + wgBase staged in LDS; csr scatter stays in the partition's
// ~156KB window. ZERO global atomics. ----
__global__ __launch_bounds__(256) void fillC_kernel(const int* __restrict__ ebufS,
                                                    const int* __restrict__ ebufD,
                                                    const int* __restrict__ blockcnt,
                                                    const int* __restrict__ wgHist,
                                                    const int* __restrict__ row_start,
                                                    int* __restrict__ csr) {
    __shared__ int cnt[PSIZE2];
    __shared__ int slotbase[PSIZE2];     // row_start + wgBase, pre-summed
    int part = blockIdx.x & (NPART2 - 1);
    int w = blockIdx.x >> 5;
    int tid = threadIdx.x;
    int nbase = part * PSIZE2;
    const int* wb = wgHist + (size_t)(part * WSUB + w) * PSIZE2;
    for (int j = tid; j < PSIZE2; j += 256) {
        cnt[j] = 0;
        slotbase[j] = row_start[nbase + j] + wb[j];
    }
    __syncthreads();
    int lo = blockcnt[part * NTB];
    int hi = (part < NPART2 - 1) ? blockcnt[(part + 1) * NTB] : NE;
    int len = hi - lo;
    int per = (len + WSUB - 1) / WSUB;
    int s0 = lo + w * per;
    int s1 = s0 + per; if (s1 > hi) s1 = hi;
    for (int i = s0 + tid; i < s1; i += 256) {
        int j = ebufD[i] - nbase;
        int local = atomicAdd(&cnt[j], 1);
        csr[slotbase[j] + local] = ebufS[i];
    }
}

// ---------------- per-layer gather-max (fp16 rows, packed half2 max) ----------------
__global__ __launch_bounds__(256) void agg_kernel(const __half* __restrict__ hh,
                                                  const int* __restrict__ row_start,
                                                  const int* __restrict__ csr,
                                                  __half* __restrict__ aggh) {
    int tid = threadIdx.x;
    int wv = tid >> 6;
    int lane = tid & 63;
    int g = lane >> 3;              // neighbor sub-slot 0..7
    int c8 = (lane & 7) * 8;        // column base (halfs)
    int n = blockIdx.x * 4 + wv;    // NN = 25000*4 exactly
    int base = row_start[n];
    int cnt = row_start[n + 1] - base;

    if (cnt > 0) {
        int clampi = cnt - 1;
        int pre = (lane <= clampi) ? lane : clampi;
        int idx = csr[base + pre];              // coalesced 256B index preload

        uint4 acc = make_uint4(0xFC00FC00u, 0xFC00FC00u, 0xFC00FC00u, 0xFC00FC00u);
        int kmax = (cnt < 64) ? cnt : 64;
        for (int k = 0; k < kmax; k += 16) {
            int k0 = k + g;
            int k1 = k + g + 8;
            int s0 = __shfl(idx, (k0 <= clampi) ? k0 : clampi, 64);
            int s1 = __shfl(idx, (k1 <= clampi) ? k1 : clampi, 64);
            if (k0 < cnt) {
                uint4 u0 = *(const uint4*)&hh[(size_t)s0 * DD + c8];
                acc.x = umax2(acc.x, u0.x);
                acc.y = umax2(acc.y, u0.y);
                acc.z = umax2(acc.z, u0.z);
                acc.w = umax2(acc.w, u0.w);
            }
            if (k1 < cnt) {
                uint4 u1 = *(const uint4*)&hh[(size_t)s1 * DD + c8];
                acc.x = umax2(acc.x, u1.x);
                acc.y = umax2(acc.y, u1.y);
                acc.z = umax2(acc.z, u1.z);
                acc.w = umax2(acc.w, u1.w);
            }
        }
        for (int k = 64 + g; k < cnt; k += 8) {   // ultra-rare tail
            int s = csr[base + k];
            uint4 u = *(const uint4*)&hh[(size_t)s * DD + c8];
            acc.x = umax2(acc.x, u.x);
            acc.y = umax2(acc.y, u.y);
            acc.z = umax2(acc.z, u.z);
            acc.w = umax2(acc.w, u.w);
        }
        // cross-group reduce (xor 8/16/32) in packed half2
        #pragma unroll
        for (int off = 8; off <= 32; off <<= 1) {
            acc.x = umax2(acc.x, (unsigned)__shfl_xor((int)acc.x, off, 64));
            acc.y = umax2(acc.y, (unsigned)__shfl_xor((int)acc.y, off, 64));
            acc.z = umax2(acc.z, (unsigned)__shfl_xor((int)acc.z, off, 64));
            acc.w = umax2(acc.w, (unsigned)__shfl_xor((int)acc.w, off, 64));
        }
        if (lane < 8) *(uint4*)&aggh[(size_t)n * DD + c8] = acc;
    } else {
        if (lane < 8) {
            uint4 z = make_uint4(0, 0, 0, 0);   // PyG empty-segment -> 0
            *(uint4*)&aggh[(size_t)n * DD + c8] = z;
        }
    }
}

// ---------------- dense update via MFMA ----------------
__global__ __launch_bounds__(256, 4) void layer_mfma_kernel(
        const __half* __restrict__ aggh,
        __half* __restrict__ hh,
        float* __restrict__ hout,
        const float* __restrict__ Wl,
        const float* __restrict__ bl,
        const float* __restrict__ Wr,
        int last) {
    __shared__ char smem[2 * MB2 * APAD * 2];   // 34816 B, reused by epilogue
    _Float16* a_s  = (_Float16*)smem;                          // [64][APAD]
    _Float16* bt_s = (_Float16*)(smem + MB2 * APAD * 2);       // [64][APAD], n-major

    int tid = threadIdx.x;
    int lane = tid & 63;
    int w = tid >> 6;
    int node0 = blockIdx.x * MB2;

    #pragma unroll
    for (int i = 0; i < 4; ++i) {
        int idx = i * 256 + tid;          // uint4 id, 1024 total
        int r = idx >> 4;
        int c4 = idx & 15;
        int node = node0 + r; if (node > NN - 1) node = NN - 1;
        const __half* srcp = (c4 < 8) ? (aggh + (size_t)node * DD + c4 * 8)
                                      : (hh + (size_t)node * DD + (c4 - 8) * 8);
        uint4 v = *(const uint4*)srcp;
        *(uint4*)&a_s[r * APAD + c4 * 8] = v;
    }
    {
        int n = tid & 63;
        int kb = tid >> 6;
        #pragma unroll
        for (int kk = 0; kk < 32; ++kk) {
            int k = kb * 32 + kk;
            float wv = (k < 64) ? Wl[k * DD + n] : Wr[(k - 64) * DD + n];
            bt_s[n * APAD + k] = (_Float16)wv;
        }
    }
    __syncthreads();

    floatx4 acc[4];
    #pragma unroll
    for (int nt = 0; nt < 4; ++nt) acc[nt] = (floatx4){0.f, 0.f, 0.f, 0.f};
    int m = lane & 15;
    int q = lane >> 4;

    #pragma unroll
    for (int ks = 0; ks < 4; ++ks) {
        half8 af = *(half8*)&a_s[(w * 16 + m) * APAD + q * 8 + ks * 32];
        #pragma unroll
        for (int nt = 0; nt < 4; ++nt) {
            half8 bf = *(half8*)&bt_s[(nt * 16 + m) * APAD + q * 8 + ks * 32];
            acc[nt] = __builtin_amdgcn_mfma_f32_16x16x32_f16(af, bf, acc[nt], 0, 0, 0);
        }
    }
    __syncthreads();

    _Float16* ch = (_Float16*)smem;                      // [64][CPADH]
    float*    cf = (float*)(smem + MB2 * CPADH * 2);     // [64][CPADF]

    #pragma unroll
    for (int nt = 0; nt < 4; ++nt) {
        int col = nt * 16 + m;
        float b = bl[col];
        #pragma unroll
        for (int r = 0; r < 4; ++r) {
            int rowl = w * 16 + q * 4 + r;
            float o = fmaxf(acc[nt][r] + b, 0.0f);
            ch[rowl * CPADH + col] = (_Float16)o;
            if (last) cf[rowl * CPADF + col] = o;
        }
    }
    __syncthreads();

    #pragma unroll
    for (int i = 0; i < 2; ++i) {
        int idx = i * 256 + tid;          // 512 uint4s
        int r = idx >> 3;
        int c4 = idx & 7;
        int node = node0 + r;
        if (node < NN) {
            uint4 v = *(uint4*)&ch[r * CPADH + c4 * 8];
            *(uint4*)&hh[(size_t)node * DD + c4 * 8] = v;
        }
    }
    if (last) {
        #pragma unroll
        for (int i = 0; i < 4; ++i) {
            int idx = i * 256 + tid;      // 1024 float4s
            int r = idx >> 4;
            int c4 = idx & 15;
            int node = node0 + r;
            if (node < NN) {
                float4 v = *(float4*)&cf[r * CPADF + c4 * 4];
                *(float4*)&hout[(size_t)node * DD + c4 * 4] = v;
            }
        }
    }
}

extern "C" void kernel_launch(void* const* d_in, const int* in_sizes, int n_in,
                              void* d_out, int out_size, void* d_ws, size_t ws_size,
                              hipStream_t stream) {
    const float* x  = (const float*)d_in[0];
    const int*   ei = (const int*)d_in[1];
    const float* Wl = (const float*)d_in[2];
    const float* bl = (const float*)d_in[3];
    const float* Wr = (const float*)d_in[4];
    float* h = (float*)d_out;

    const int* src = ei;
    const int* dst = ei + NE;

    char* ws = (char*)d_ws;
    __half* aggh     = (__half*)ws;  ws += (size_t)NN * DD * sizeof(__half);  // 12.8 MB
    __half* hh       = (__half*)ws;  ws += (size_t)NN * DD * sizeof(__half);  // 12.8 MB
    int* row_start   = (int*)ws;     ws += (size_t)(NN + 16) * sizeof(int);
    int* deg         = (int*)ws;     ws += (size_t)NN * sizeof(int);
    int* blocksums   = (int*)ws;     ws += 128 * sizeof(int);
    int* blockcnt    = (int*)ws;     ws += (size_t)(SCANA_N + 16) * sizeof(int);
    int* wgHist      = (int*)ws;     ws += (size_t)NPART2 * WSUB * PSIZE2 * sizeof(int); // 3.2 MB
    int* csr         = (int*)ws;                                              // 5 MB

    // edge buckets reuse the aggh region (dead until first agg_kernel)
    int* ebufS = (int*)aggh;
    int* ebufD = ebufS + NE;                     // 2*NE ints = 10 MB <= 12.8 MB

    cast_kernel<<<(NN * DD / 4) / 256, 256, 0, stream>>>(x, hh);

    countA_kernel<<<NTB, 256, 0, stream>>>(dst, blockcnt);
    scanA_kernel<<<1, 1024, 0, stream>>>(blockcnt);
    scatterA_kernel<<<NTB, 256, 0, stream>>>(src, dst, blockcnt, ebufS, ebufD);
    countC_kernel<<<NPART2 * WSUB, 256, 0, stream>>>(ebufD, blockcnt, wgHist);
    sumC_kernel<<<(NN + 255) / 256, 256, 0, stream>>>(wgHist, deg);
    scan1_kernel<<<SCAN_NB, SCAN_B, 0, stream>>>(deg, row_start, blocksums);
    scan2_kernel<<<1, 128, 0, stream>>>(blocksums);
    scan3_kernel<<<SCAN_NB, SCAN_B, 0, stream>>>(row_start, blocksums);
    fillC_kernel<<<NPART2 * WSUB, 256, 0, stream>>>(ebufS, ebufD, blockcnt, wgHist, row_start, csr);

    for (int l = 0; l < NL; ++l) {
        agg_kernel<<<NN / 4, 256, 0, stream>>>(hh, row_start, csr, aggh);
        layer_mfma_kernel<<<L2BLOCKS, 256, 0, stream>>>(
            aggh, hh, h, Wl + (size_t)l * DD * DD, bl + (size_t)l * DD, Wr + (size_t)l * DD * DD,
            (l == NL - 1) ? 1 : 0);
    }
}

// Round 13
// 317.453 us; speedup vs baseline: 1.4135x; 1.0227x over previous
//
#include <hip/hip_runtime.h>
#include <hip/hip_fp16.h>
#include <stdint.h>

#define NN 100000
#define NE 1250000
#define DD 64
#define NL 4

#define NPART3 64            // partitions; one WG owns one partition in fillD
#define PSIZE3 1563          // nodes per partition (64*1563 = 100032 >= NN)
#define TILE4 1024           // int4s per radix tile = 4096 edges
#define NTB ((NE / 4 + TILE4 - 1) / TILE4)        // 306 tiles
#define SCANA_N (NPART3 * NTB)                    // 19584
#define SRCBITS 17           // src < 100000 < 2^17; dlocal < 1563 < 2^11

#define MB2 64               // nodes per MFMA layer block
#define L2BLOCKS ((NN + MB2 - 1) / MB2)   // 1563
#define APAD 136             // halfs per A/Bt LDS row
#define CPADH 72             // halfs per C row
#define CPADF 68             // floats per C row

typedef _Float16 half8 __attribute__((ext_vector_type(8)));
typedef _Float16 half2v __attribute__((ext_vector_type(2)));
typedef float floatx4 __attribute__((ext_vector_type(4)));
typedef int intx4 __attribute__((ext_vector_type(4)));

__device__ __forceinline__ float2 h2f2(unsigned u) {
    __half2 h = *reinterpret_cast<__half2*>(&u);
    return __half22float2(h);
}
__device__ __forceinline__ unsigned f2h2(float a, float b) {
    __half2 h = __floats2half2_rn(a, b);
    return *reinterpret_cast<unsigned*>(&h);
}
// packed fp16 max on raw bits (maps to v_pk_max_f16)
__device__ __forceinline__ unsigned umax2(unsigned a, unsigned b) {
    half2v x = *reinterpret_cast<half2v*>(&a);
    half2v y = *reinterpret_cast<half2v*>(&b);
    half2v r = __builtin_elementwise_max(x, y);
    return *reinterpret_cast<unsigned*>(&r);
}

// ---- x (fp32) -> hh (fp16) ----
__global__ __launch_bounds__(256) void cast_kernel(const float* __restrict__ x,
                                                   __half* __restrict__ hh) {
    int i = blockIdx.x * 256 + threadIdx.x;
    float4 v = ((const float4*)x)[i];
    uint2 u;
    u.x = f2h2(v.x, v.y);
    u.y = f2h2(v.z, v.w);
    ((uint2*)hh)[i] = u;
}

// ---------------- radix bucketing: edges -> 64 dst-partition buckets ----------------
__global__ __launch_bounds__(256) void countA_kernel(const int* __restrict__ dst,
                                                     int* __restrict__ blockcnt) {
    __shared__ int cnt[NPART3];
    int tid = threadIdx.x;
    if (tid < NPART3) cnt[tid] = 0;
    __syncthreads();
    int b = blockIdx.x;
    #pragma unroll
    for (int r = 0; r < 4; ++r) {
        int i4 = b * TILE4 + r * 256 + tid;
        if (i4 < NE / 4) {
            intx4 d = __builtin_nontemporal_load(&((const intx4*)dst)[i4]);
            atomicAdd(&cnt[(unsigned)d.x / PSIZE3], 1);
            atomicAdd(&cnt[(unsigned)d.y / PSIZE3], 1);
            atomicAdd(&cnt[(unsigned)d.z / PSIZE3], 1);
            atomicAdd(&cnt[(unsigned)d.w / PSIZE3], 1);
        }
    }
    __syncthreads();
    if (tid < NPART3) blockcnt[tid * NTB + b] = cnt[tid];
}

// exclusive scan over NPART3*NTB = 19584 counts (bucket-major -> global offsets)
__global__ __launch_bounds__(1024) void scanA_kernel(int* __restrict__ blockcnt) {
    __shared__ int sm[1024];
    int tid = threadIdx.x;
    int base = tid * 20;
    int e[20];
    int s = 0;
    #pragma unroll
    for (int j = 0; j < 20; ++j) {
        e[j] = (base + j < SCANA_N) ? blockcnt[base + j] : 0;
        s += e[j];
    }
    sm[tid] = s;
    __syncthreads();
    for (int off = 1; off < 1024; off <<= 1) {
        int v = (tid >= off) ? sm[tid - off] : 0;
        __syncthreads();
        sm[tid] += v;
        __syncthreads();
    }
    int run = sm[tid] - s;
    #pragma unroll
    for (int j = 0; j < 20; ++j) {
        if (base + j < SCANA_N) {
            blockcnt[base + j] = run;
            run += e[j];
        }
    }
}

// scatter packed (dlocal<<17 | src) into bucket order — one store per edge
__global__ __launch_bounds__(256) void scatterA_kernel(const int* __restrict__ src,
                                                       const int* __restrict__ dst,
                                                       const int* __restrict__ blockcnt,
                                                       int* __restrict__ ebufP) {
    __shared__ int cur[NPART3];
    int tid = threadIdx.x;
    int b = blockIdx.x;
    if (tid < NPART3) cur[tid] = blockcnt[tid * NTB + b];
    __syncthreads();
    #pragma unroll
    for (int r = 0; r < 4; ++r) {
        int i4 = b * TILE4 + r * 256 + tid;
        if (i4 < NE / 4) {
            intx4 d = __builtin_nontemporal_load(&((const intx4*)dst)[i4]);
            intx4 s = __builtin_nontemporal_load(&((const intx4*)src)[i4]);
            int part, p;
            part = (unsigned)d.x / PSIZE3; p = atomicAdd(&cur[part], 1);
            ebufP[p] = ((d.x - part * PSIZE3) << SRCBITS) | s.x;
            part = (unsigned)d.y / PSIZE3; p = atomicAdd(&cur[part], 1);
            ebufP[p] = ((d.y - part * PSIZE3) << SRCBITS) | s.y;
            part = (unsigned)d.z / PSIZE3; p = atomicAdd(&cur[part], 1);
            ebufP[p] = ((d.z - part * PSIZE3) << SRCBITS) | s.z;
            part = (unsigned)d.w / PSIZE3; p = atomicAdd(&cur[part], 1);
            ebufP[p] = ((d.w - part * PSIZE3) << SRCBITS) | s.w;
        }
    }
}

// ---- ONE kernel replaces countC/sumC/scan1/scan2/scan3/fillC: each WG owns a
// whole partition. LDS hist -> in-WG exclusive scan -> row_start write -> csr
// scatter. Zero global atomics anywhere. ----
__global__ __launch_bounds__(1024) void fillD_kernel(const int* __restrict__ ebufP,
                                                     const int* __restrict__ blockcnt,
                                                     int* __restrict__ row_start,
                                                     int* __restrict__ csr) {
    __shared__ int cnt[PSIZE3];
    __shared__ int localstart[PSIZE3];
    __shared__ int partial[1024];
    int part = blockIdx.x;
    int tid = threadIdx.x;
    int nbase = part * PSIZE3;
    int base = blockcnt[part * NTB];
    int hi = (part < NPART3 - 1) ? blockcnt[(part + 1) * NTB] : NE;

    for (int j = tid; j < PSIZE3; j += 1024) cnt[j] = 0;
    __syncthreads();

    // pass 1: histogram
    for (int i = base + tid; i < hi; i += 1024)
        atomicAdd(&cnt[(unsigned)ebufP[i] >> SRCBITS], 1);
    __syncthreads();

    // in-WG exclusive scan over PSIZE3 entries (2 elems/thread + block scan)
    int j0 = tid * 2;
    int e0 = (j0 < PSIZE3) ? cnt[j0] : 0;
    int e1 = (j0 + 1 < PSIZE3) ? cnt[j0 + 1] : 0;
    int s = e0 + e1;
    partial[tid] = s;
    __syncthreads();
    for (int off = 1; off < 1024; off <<= 1) {
        int v = (tid >= off) ? partial[tid - off] : 0;
        __syncthreads();
        partial[tid] += v;
        __syncthreads();
    }
    int run = partial[tid] - s;
    if (j0 < PSIZE3) localstart[j0] = run;
    if (j0 + 1 < PSIZE3) localstart[j0 + 1] = run + e0;
    __syncthreads();

    // row_start for this partition's nodes (+ global sentinel)
    int nmax = NN - nbase; if (nmax > PSIZE3) nmax = PSIZE3;
    for (int j = tid; j < nmax; j += 1024)
        row_start[nbase + j] = base + localstart[j];
    if (part == NPART3 - 1 && tid == 0) row_start[NN] = NE;

    // reset cnt for rank assignment
    for (int j = tid; j < PSIZE3; j += 1024) cnt[j] = 0;
    __syncthreads();

    // pass 2: scatter csr (LDS rank only; csr window ~L2-local)
    for (int i = base + tid; i < hi; i += 1024) {
        int p = ebufP[i];
        int dl = (unsigned)p >> SRCBITS;
        int local = atomicAdd(&cnt[dl], 1);
        csr[base + localstart[dl] + local] = p & ((1 << SRCBITS) - 1);
    }
}

// ---------------- per-layer gather-max (fp16 rows, packed half2 max) ----------------
__global__ __launch_bounds__(256) void agg_kernel(const __half* __restrict__ hh,
                                                  const int* __restrict__ row_start,
                                                  const int* __restrict__ csr,
                                                  __half* __restrict__ aggh) {
    int tid = threadIdx.x;
    int wv = tid >> 6;
    int lane = tid & 63;
    int g = lane >> 3;              // neighbor sub-slot 0..7
    int c8 = (lane & 7) * 8;        // column base (halfs)
    int n = blockIdx.x * 4 + wv;    // NN = 25000*4 exactly
    int base = row_start[n];
    int cnt = row_start[n + 1] - base;

    if (cnt > 0) {
        int clampi = cnt - 1;
        int pre = (lane <= clampi) ? lane : clampi;
        int idx = csr[base + pre];              // coalesced 256B index preload

        uint4 acc = make_uint4(0xFC00FC00u, 0xFC00FC00u, 0xFC00FC00u, 0xFC00FC00u);
        int kmax = (cnt < 64) ? cnt : 64;
        for (int k = 0; k < kmax; k += 16) {
            int k0 = k + g;
            int k1 = k + g + 8;
            int s0 = __shfl(idx, (k0 <= clampi) ? k0 : clampi, 64);
            int s1 = __shfl(idx, (k1 <= clampi) ? k1 : clampi, 64);
            if (k0 < cnt) {
                uint4 u0 = *(const uint4*)&hh[(size_t)s0 * DD + c8];
                acc.x = umax2(acc.x, u0.x);
                acc.y = umax2(acc.y, u0.y);
                acc.z = umax2(acc.z, u0.z);
                acc.w = umax2(acc.w, u0.w);
            }
            if (k1 < cnt) {
                uint4 u1 = *(const uint4*)&hh[(size_t)s1 * DD + c8];
                acc.x = umax2(acc.x, u1.x);
                acc.y = umax2(acc.y, u1.y);
                acc.z = umax2(acc.z, u1.z);
                acc.w = umax2(acc.w, u1.w);
            }
        }
        for (int k = 64 + g; k < cnt; k += 8) {   // ultra-rare tail
            int s = csr[base + k];
            uint4 u = *(const uint4*)&hh[(size_t)s * DD + c8];
            acc.x = umax2(acc.x, u.x);
            acc.y = umax2(acc.y, u.y);
            acc.z = umax2(acc.z, u.z);
            acc.w = umax2(acc.w, u.w);
        }
        // cross-group reduce (xor 8/16/32) in packed half2
        #pragma unroll
        for (int off = 8; off <= 32; off <<= 1) {
            acc.x = umax2(acc.x, (unsigned)__shfl_xor((int)acc.x, off, 64));
            acc.y = umax2(acc.y, (unsigned)__shfl_xor((int)acc.y, off, 64));
            acc.z = umax2(acc.z, (unsigned)__shfl_xor((int)acc.z, off, 64));
            acc.w = umax2(acc.w, (unsigned)__shfl_xor((int)acc.w, off, 64));
        }
        if (lane < 8) *(uint4*)&aggh[(size_t)n * DD + c8] = acc;
    } else {
        if (lane < 8) {
            uint4 z = make_uint4(0, 0, 0, 0);   // PyG empty-segment -> 0
            *(uint4*)&aggh[(size_t)n * DD + c8] = z;
        }
    }
}

// ---------------- dense update via MFMA ----------------
__global__ __launch_bounds__(256, 4) void layer_mfma_kernel(
        const __half* __restrict__ aggh,
        __half* __restrict__ hh,
        float* __restrict__ hout,
        const float* __restrict__ Wl,
        const float* __restrict__ bl,
        const float* __restrict__ Wr,
        int last) {
    __shared__ char smem[2 * MB2 * APAD * 2];   // 34816 B, reused by epilogue
    _Float16* a_s  = (_Float16*)smem;                          // [64][APAD]
    _Float16* bt_s = (_Float16*)(smem + MB2 * APAD * 2);       // [64][APAD], n-major

    int tid = threadIdx.x;
    int lane = tid & 63;
    int w = tid >> 6;
    int node0 = blockIdx.x * MB2;

    #pragma unroll
    for (int i = 0; i < 4; ++i) {
        int idx = i * 256 + tid;          // uint4 id, 1024 total
        int r = idx >> 4;
        int c4 = idx & 15;
        int node = node0 + r; if (node > NN - 1) node = NN - 1;
        const __half* srcp = (c4 < 8) ? (aggh + (size_t)node * DD + c4 * 8)
                                      : (hh + (size_t)node * DD + (c4 - 8) * 8);
        uint4 v = *(const uint4*)srcp;
        *(uint4*)&a_s[r * APAD + c4 * 8] = v;
    }
    {
        int n = tid & 63;
        int kb = tid >> 6;
        #pragma unroll
        for (int kk = 0; kk < 32; ++kk) {
            int k = kb * 32 + kk;
            float wv = (k < 64) ? Wl[k * DD + n] : Wr[(k - 64) * DD + n];
            bt_s[n * APAD + k] = (_Float16)wv;
        }
    }
    __syncthreads();

    floatx4 acc[4];
    #pragma unroll
    for (int nt = 0; nt < 4; ++nt) acc[nt] = (floatx4){0.f, 0.f, 0.f, 0.f};
    int m = lane & 15;
    int q = lane >> 4;

    #pragma unroll
    for (int ks = 0; ks < 4; ++ks) {
        half8 af = *(half8*)&a_s[(w * 16 + m) * APAD + q * 8 + ks * 32];
        #pragma unroll
        for (int nt = 0; nt < 4; ++nt) {
            half8 bf = *(half8*)&bt_s[(nt * 16 + m) * APAD + q * 8 + ks * 32];
            acc[nt] = __builtin_amdgcn_mfma_f32_16x16x32_f16(af, bf, acc[nt], 0, 0, 0);
        }
    }
    __syncthreads();

    _Float16* ch = (_Float16*)smem;                      // [64][CPADH]
    float*    cf = (float*)(smem + MB2 * CPADH * 2);     // [64][CPADF]

    #pragma unroll
    for (int nt = 0; nt < 4; ++nt) {
        int col = nt * 16 + m;
        float b = bl[col];
        #pragma unroll
        for (int r = 0; r < 4; ++r) {
            int rowl = w * 16 + q * 4 + r;
            float o = fmaxf(acc[nt][r] + b, 0.0f);
            ch[rowl * CPADH + col] = (_Float16)o;
            if (last) cf[rowl * CPADF + col] = o;
        }
    }
    __syncthreads();

    #pragma unroll
    for (int i = 0; i < 2; ++i) {
        int idx = i * 256 + tid;          // 512 uint4s
        int r = idx >> 3;
        int c4 = idx & 7;
        int node = node0 + r;
        if (node < NN) {
            uint4 v = *(uint4*)&ch[r * CPADH + c4 * 8];
            *(uint4*)&hh[(size_t)node * DD + c4 * 8] = v;
        }
    }
    if (last) {
        #pragma unroll
        for (int i = 0; i < 4; ++i) {
            int idx = i * 256 + tid;      // 1024 float4s
            int r = idx >> 4;
            int c4 = idx & 15;
            int node = node0 + r;
            if (node < NN) {
                float4 v = *(float4*)&cf[r * CPADF + c4 * 4];
                *(float4*)&hout[(size_t)node * DD + c4 * 4] = v;
            }
        }
    }
}

extern "C" void kernel_launch(void* const* d_in, const int* in_sizes, int n_in,
                              void* d_out, int out_size, void* d_ws, size_t ws_size,
                              hipStream_t stream) {
    const float* x  = (const float*)d_in[0];
    const int*   ei = (const int*)d_in[1];
    const float* Wl = (const float*)d_in[2];
    const float* bl = (const float*)d_in[3];
    const float* Wr = (const float*)d_in[4];
    float* h = (float*)d_out;

    const int* src = ei;
    const int* dst = ei + NE;

    char* ws = (char*)d_ws;
    __half* aggh     = (__half*)ws;  ws += (size_t)NN * DD * sizeof(__half);  // 12.8 MB
    __half* hh       = (__half*)ws;  ws += (size_t)NN * DD * sizeof(__half);  // 12.8 MB
    int* row_start   = (int*)ws;     ws += (size_t)(NN + 16) * sizeof(int);
    int* blockcnt    = (int*)ws;     ws += (size_t)(SCANA_N + 16) * sizeof(int);
    int* csr         = (int*)ws;                                              // 5 MB

    // packed edge bucket reuses the aggh region (dead until first agg_kernel)
    int* ebufP = (int*)aggh;                     // NE ints = 5 MB <= 12.8 MB

    cast_kernel<<<(NN * DD / 4) / 256, 256, 0, stream>>>(x, hh);

    countA_kernel<<<NTB, 256, 0, stream>>>(dst, blockcnt);
    scanA_kernel<<<1, 1024, 0, stream>>>(blockcnt);
    scatterA_kernel<<<NTB, 256, 0, stream>>>(src, dst, blockcnt, ebufP);
    fillD_kernel<<<NPART3, 1024, 0, stream>>>(ebufP, blockcnt, row_start, csr);

    for (int l = 0; l < NL; ++l) {
        agg_kernel<<<NN / 4, 256, 0, stream>>>(hh, row_start, csr, aggh);
        layer_mfma_kernel<<<L2BLOCKS, 256, 0, stream>>>(
            aggh, hh, h, Wl + (size_t)l * DD * DD, bl + (size_t)l * DD, Wr + (size_t)l * DD * DD,
            (l == NL - 1) ? 1 : 0);
    }
}